// Round 2
// baseline (1219.248 us; speedup 1.0000x reference)
//
#include <hip/hip_runtime.h>
#include <stdint.h>

#define NB3 8112
#define NB4 2028
#define NB5 507
#define NTOT 10647           // 8112 + 2028 + 507
#define NBATCH 4
#define NCLS 20
#define NW32 333             // ceil(10647 / 32)
#define NW64 167             // ceil(10647 / 64)
#define LDS_CAP 9984         // boxes staged in LDS (fallback kernel)
#define CONF_THR_F 0.1f
#define IOU_THR_F 0.45f

typedef unsigned long long u64;

// ---------------------------------------------------------------------------
// Kernel A: per-box score / class argmax / sort key
// ---------------------------------------------------------------------------
__global__ void prep_kernel(const float* __restrict__ p3b, const float* __restrict__ p3c, const float* __restrict__ p3k,
                            const float* __restrict__ p4b, const float* __restrict__ p4c, const float* __restrict__ p4k,
                            const float* __restrict__ p5b, const float* __restrict__ p5c, const float* __restrict__ p5k,
                            uint64_t* __restrict__ keys, float4* __restrict__ boxes_cat,
                            float* __restrict__ score, int* __restrict__ clsidx, uint32_t* __restrict__ svout)
{
#pragma clang fp contract(off)
    int idx = blockIdx.x * 256 + threadIdx.x;
    if (idx >= NBATCH * NTOT) return;
    int b = idx / NTOT;
    int i = idx - b * NTOT;

    const float* bx; const float* cf; const float* cl; int n, off;
    if (i < NB3)            { bx = p3b; cf = p3c; cl = p3k; n = NB3; off = i; }
    else if (i < NB3 + NB4) { bx = p4b; cf = p4c; cl = p4k; n = NB4; off = i - NB3; }
    else                    { bx = p5b; cf = p5c; cl = p5k; n = NB5; off = i - NB3 - NB4; }

    size_t e = (size_t)b * n + off;
    float4 box = *(const float4*)(bx + e * 4);
    float conf = cf[e];
    const float* c = cl + e * NCLS;
    float m = c[0]; int mi = 0;
    #pragma unroll
    for (int k = 1; k < NCLS; ++k) { float v = c[k]; if (v > m) { m = v; mi = k; } }

    bool valid = conf > CONF_THR_F;
    float s = valid ? conf * m : 0.0f;           // exact: single f32 mul, no fma
    uint32_t sb = __float_as_uint(s);            // s >= 0 -> bits monotonic
    keys[idx]      = ((uint64_t)sb << 32) | (uint32_t)(0xFFFFFFFFu - (uint32_t)i);
    boxes_cat[idx] = box;
    score[idx]     = s;
    clsidx[idx]    = mi;
    svout[idx]     = valid ? 1u : 0u;
}

// ---------------------------------------------------------------------------
// Kernel B: stable descending rank sort (rank = #keys strictly greater),
// scatter sorted arrays, build valid bitmap (u64 words) per image
// ---------------------------------------------------------------------------
__global__ void rank_kernel(const uint64_t* __restrict__ keys,
                            const float4* __restrict__ boxes_cat,
                            const float* __restrict__ score,
                            const int* __restrict__ clsidx,
                            const uint32_t* __restrict__ sv,
                            float4* __restrict__ sboxes, float* __restrict__ sscore,
                            int* __restrict__ scls, uint32_t* __restrict__ ssv,
                            u64* __restrict__ validbits, int* __restrict__ nvalid)
{
    int b = blockIdx.y;
    int i = blockIdx.x * 256 + threadIdx.x;
    const uint64_t* kb = keys + (size_t)b * NTOT;
    uint64_t mykey = (i < NTOT) ? kb[i] : 0ull;

    __shared__ uint64_t tile[256];
    int rank = 0;
    for (int t0 = 0; t0 < NTOT; t0 += 256) {
        int j = t0 + threadIdx.x;
        tile[threadIdx.x] = (j < NTOT) ? kb[j] : 0ull;   // 0 never > any real key
        __syncthreads();
        #pragma unroll 8
        for (int t = 0; t < 256; ++t) rank += (tile[t] > mykey) ? 1 : 0;
        __syncthreads();
    }

    if (i < NTOT) {
        size_t src = (size_t)b * NTOT + i;
        size_t dst = (size_t)b * NTOT + rank;
        sboxes[dst] = boxes_cat[src];
        sscore[dst] = score[src];
        scls[dst]   = clsidx[src];
        uint32_t v  = sv[src];
        ssv[dst]    = v;
        if (v) {
            atomicOr(&validbits[(size_t)b * NW64 + (rank >> 6)], 1ull << (rank & 63));
            atomicMax(&nvalid[b], rank + 1);
        }
    }
}

// ---------------------------------------------------------------------------
// Kernel C1 (fast path): build suppression bit-matrix + compact diag blocks
// + super-diagonal blocks.
// mask[(b*NTOT + i)*NW64 + c] = 64-bit word: bit k set iff IoU(i, c*64+k)>thr
// and (c*64+k) > i. Only upper-triangle chunks (c >= r) are written.
// diag [(b*NW64 + g)*64 + lane] = mask word of row g*64+lane at column-chunk g
// sdiag[(b*NW64 + g)*64 + lane] = mask word of row g*64+lane at column-chunk g+1
// (both coalesced copies for resolve_kernel's decision pipeline).
// ---------------------------------------------------------------------------
__global__ void __launch_bounds__(256) mask_build(const float4* __restrict__ sboxes,
                                                  u64* __restrict__ mask,
                                                  u64* __restrict__ diag,
                                                  u64* __restrict__ sdiag)
{
#pragma clang fp contract(off)
    int c = blockIdx.y;
    if (c < blockIdx.x * 4) return;              // whole block below diagonal
    int b = blockIdx.z;
    int sub = threadIdx.x >> 6;
    int lane = threadIdx.x & 63;
    int r = blockIdx.x * 4 + sub;

    __shared__ float4 cb[64];
    __shared__ float  ca[64];
    if (threadIdx.x < 64) {
        int j = c * 64 + threadIdx.x;
        float4 bj = sboxes[(size_t)b * NTOT + (j < NTOT ? j : NTOT - 1)];
        cb[threadIdx.x] = bj;
        ca[threadIdx.x] = (bj.z - bj.x) * (bj.w - bj.y);
    }
    __syncthreads();

    if (r >= NW64 || c < r) return;              // wave below diagonal / OOB
    int i = r * 64 + lane;
    float4 bi = sboxes[(size_t)b * NTOT + (i < NTOT ? i : NTOT - 1)];
    float ax1 = bi.x, ay1 = bi.y, ax2 = bi.z, ay2 = bi.w;
    float area_i = (ax2 - ax1) * (ay2 - ay1);

    u64 m = 0;
    #pragma unroll 8
    for (int k = 0; k < 64; ++k) {
        float4 bj = cb[k];
        float xx1 = fmaxf(bj.x, ax1);
        float yy1 = fmaxf(bj.y, ay1);
        float xx2 = fminf(bj.z, ax2);
        float yy2 = fminf(bj.w, ay2);
        float w = fmaxf(xx2 - xx1, 0.0f);
        float h = fmaxf(yy2 - yy1, 0.0f);
        float inter = w * h;
        float iou = inter / ((area_i + ca[k]) - inter);   // matches ref op order
        bool set = (iou > IOU_THR_F) && (c > r || k > lane) && (c * 64 + k < NTOT);
        m |= (u64)set << k;
    }
    if (i < NTOT) {
        mask[((size_t)b * NTOT + i) * NW64 + c] = m;
        if (c == r)     diag [((size_t)b * NW64 + r) * 64 + lane] = m;
        if (c == r + 1) sdiag[((size_t)b * NW64 + r) * 64 + lane] = m;
    }
}

// ---------------------------------------------------------------------------
// Kernel C2 (fast path): greedy resolve, one 1024-thread block per image,
// software-pipelined so NO global-load latency sits between consecutive
// group decisions:
//   * decide(g) -> word g+1 comes from the super-diagonal block (prefetched a
//     full iteration ahead; OR'd during the shfl chain itself).
//   * words g+2.. are loaded at iteration g (predicated-to-zero registers),
//     carried ACROSS the barrier, committed via sparse LDS atomicOr at
//     iteration g+1 -- a full iteration of slack hides the latency.
//   * raw s_barrier (manual lgkmcnt(0) only, no vmcnt drain) keeps all
//     prefetches in flight across iterations; ONE barrier per group.
//   * every wave runs the (uniform) chain redundantly and captures its own
//     kept-row slots (s==wv+16t) -> no klist LDS handoff needed.
//   * in-group suppressions recorded as alive & ~kept (diagonal word is no
//     longer loaded). Benign race on rem_s[g]: greedy(kept ∪ S)=kept for any
//     subset S of the suppressed set, so late readers still agree.
// ---------------------------------------------------------------------------
static __device__ __forceinline__ void bar_sync()
{
    asm volatile("s_waitcnt lgkmcnt(0)" ::: "memory");
    __builtin_amdgcn_s_barrier();
    asm volatile("" ::: "memory");
}

__global__ void __launch_bounds__(1024) resolve_kernel(const u64* __restrict__ mask,
                                                       const u64* __restrict__ diag,
                                                       const u64* __restrict__ sdiag,
                                                       const u64* __restrict__ validbits,
                                                       u64* __restrict__ rem_out)
{
    int b = blockIdx.x;
    int tid = threadIdx.x;
    int lane = tid & 63;
    int wv = tid >> 6;
    const u64* M  = mask  + (size_t)b * NTOT * NW64;
    const u64* D  = diag  + (size_t)b * NW64 * 64;
    const u64* SD = sdiag + (size_t)b * NW64 * 64;
    const u64* V  = validbits + (size_t)b * NW64;

    __shared__ u64 rem_s[NW64 + 1];              // +1 pad absorbs g=last near-OR
    __shared__ u64 v_s[NW64];

    for (int t = tid; t < NW64; t += 1024) { rem_s[t] = 0ull; v_s[t] = V[t]; }
    if (tid == 0) rem_s[NW64] = 0ull;

    u64 dl  = D[lane];                           // diag word, group 0
    u64 sdl = SD[lane];                          // superdiag word, group 0

    u64 df[4][3];                                // deferred far-OR payload
    #pragma unroll
    for (int t = 0; t < 4; ++t) {
        #pragma unroll
        for (int c = 0; c < 3; ++c) df[t][c] = 0ull;
    }
    int r0 = 0, r1 = 0, r2 = 0, r3 = 0;          // captured kept-row slots

    bar_sync();

    for (int g = 0; g < NW64; ++g) {
        // 1. prefetch next group's diag/superdiag (stays in flight across bar)
        int gn = (g + 1 < NW64) ? g + 1 : g;
        u64 dn  = D [(size_t)gn * 64 + lane];
        u64 sdn = SD[(size_t)gn * 64 + lane];

        // 2. decide: greedy chain, identical (uniform) in every wave.
        //    w1 (word g+1 contribution) rides the chain via the superdiag.
        //    Wave wv captures kept rows #wv, #wv+16, #wv+32, #wv+48.
        u64 alive = v_s[g] & ~rem_s[g];
        u64 kept = 0, pend = alive, w1 = 0;
        int s = 0;
        while (pend) {
            int i = __ffsll((unsigned long long)pend) - 1;
            kept |= 1ull << i;
            u64 d = __shfl(dl, i, 64);
            w1 |= __shfl(sdl, i, 64);
            r0 = (s == wv)      ? i : r0;
            r1 = (s == wv + 16) ? i : r1;
            r2 = (s == wv + 32) ? i : r2;
            r3 = (s == wv + 48) ? i : r3;
            pend &= ~(d | (1ull << i));
            ++s;
        }
        int nk = s;

        // 3. record in-group suppressions + near word g+1
        if (tid == 0) {
            u64 supp = alive & ~kept;
            if (supp) atomicOr((unsigned long long*)&rem_s[g],     (unsigned long long)supp);
            if (w1)   atomicOr((unsigned long long*)&rem_s[g + 1], (unsigned long long)w1);
        }

        // 4. commit deferred far-ORs from the previous group (targets >= g+1;
        //    sparse -- most df words are zero and skip the atomic)
        #pragma unroll
        for (int t = 0; t < 4; ++t) {
            #pragma unroll
            for (int c = 0; c < 3; ++c) {
                if (df[t][c])
                    atomicOr((unsigned long long*)&rem_s[g + 1 + (c << 6) + lane],
                             (unsigned long long)df[t][c]);
            }
        }

        // 5. issue this group's far loads (words g+2..166), predicated to 0;
        //    results are consumed one iteration later (step 4 of g+1)
        #pragma unroll
        for (int t = 0; t < 4; ++t) {
            bool has = (wv + (t << 4)) < nk;
            int  rr  = (t == 0) ? r0 : (t == 1) ? r1 : (t == 2) ? r2 : r3;
            const u64* R = M + (size_t)(g * 64 + rr) * NW64;
            #pragma unroll
            for (int c = 0; c < 3; ++c) {
                int w = g + 2 + (c << 6) + lane;
                df[t][c] = (has && w < NW64) ? R[w] : 0ull;
            }
        }

        bar_sync();                               // LDS coherent; VMEM in flight
        dl = dn; sdl = sdn;
    }
    // df from the final groups target words >= NW64 -> predicated to zero. OK.

    for (int t = tid; t < NW64; t += 1024)
        rem_out[(size_t)b * NW64 + t] = rem_s[t];
}

// ---------------------------------------------------------------------------
// Fallback (small ws): original single-block NMS. Writes u32 words into the
// same u64 rem buffer (little-endian layout makes bit positions identical).
// ---------------------------------------------------------------------------
extern __shared__ unsigned char nms_smem[];

__global__ void __launch_bounds__(1024) nms_kernel(const float4* __restrict__ sboxes,
                                                   const uint32_t* __restrict__ ssv,
                                                   const int* __restrict__ nvalid_arr,
                                                   uint32_t* __restrict__ supp_out)
{
#pragma clang fp contract(off)
    int b = blockIdx.x;
    float4*   lbox = (float4*)nms_smem;
    uint32_t* supp = (uint32_t*)(nms_smem + (size_t)LDS_CAP * 16);
    uint32_t* svb  = supp + NW32;

    int nv = nvalid_arr[b];
    const float4* gb = sboxes + (size_t)b * NTOT;
    const uint32_t* gv = ssv + (size_t)b * NTOT;

    for (int t = threadIdx.x; t < NW32; t += 1024) { supp[t] = 0u; svb[t] = 0u; }
    __syncthreads();
    for (int t = threadIdx.x; t < nv; t += 1024) {
        if (t < LDS_CAP) lbox[t] = gb[t];
        if (gv[t]) atomicOr(&svb[t >> 5], 1u << (t & 31));
    }
    __syncthreads();

    for (int i = 0; i < nv; ++i) {
        uint32_t sw = supp[i >> 5];
        if ((sw >> (i & 31)) & 1u) continue;
        uint32_t vw = svb[i >> 5];
        if (!((vw >> (i & 31)) & 1u)) continue;

        float4 bi = (i < LDS_CAP) ? lbox[i] : gb[i];
        float ax1 = bi.x, ay1 = bi.y, ax2 = bi.z, ay2 = bi.w;
        float area_i = (ax2 - ax1) * (ay2 - ay1);

        for (int j = i + 1 + (int)threadIdx.x; j < nv; j += 1024) {
            float4 bj = (j < LDS_CAP) ? lbox[j] : gb[j];
            float xx1 = fmaxf(bj.x, ax1);
            float yy1 = fmaxf(bj.y, ay1);
            float xx2 = fminf(bj.z, ax2);
            float yy2 = fminf(bj.w, ay2);
            float w = fmaxf(xx2 - xx1, 0.0f);
            float h = fmaxf(yy2 - yy1, 0.0f);
            float inter  = w * h;
            float area_j = (bj.z - bj.x) * (bj.w - bj.y);
            float iou = inter / ((area_i + area_j) - inter);
            if (iou > IOU_THR_F) atomicOr(&supp[j >> 5], 1u << (j & 31));
        }
        __syncthreads();
    }

    __syncthreads();
    // u64 layout: u32 word w of image b lives at u32-index b*(2*NW64) + w
    for (int t = threadIdx.x; t < NW32; t += 1024)
        supp_out[(size_t)b * (2 * NW64) + t] = supp[t];
}

// ---------------------------------------------------------------------------
// Kernel D: assemble outputs: dets [B,N,6] then keep [B,N] (as 0/1 floats)
// ---------------------------------------------------------------------------
__global__ void out_kernel(const float4* __restrict__ sboxes, const float* __restrict__ sscore,
                           const int* __restrict__ scls, const uint32_t* __restrict__ ssv,
                           const u64* __restrict__ rem, float* __restrict__ out)
{
    int idx = blockIdx.x * 256 + threadIdx.x;
    if (idx >= NBATCH * NTOT) return;
    int b = idx / NTOT;
    int p = idx - b * NTOT;

    float4 box = sboxes[idx];
    u64 rw = rem[(size_t)b * NW64 + (p >> 6)];
    bool keep = (ssv[idx] != 0u) && !((rw >> (p & 63)) & 1ull);
    float sc = keep ? sscore[idx] : 0.0f;

    float* d = out + (size_t)idx * 6;
    d[0] = box.x; d[1] = box.y; d[2] = box.z; d[3] = box.w;
    d[4] = sc;    d[5] = (float)scls[idx];
    out[(size_t)NBATCH * NTOT * 6 + idx] = keep ? 1.0f : 0.0f;
}

// ---------------------------------------------------------------------------
extern "C" void kernel_launch(void* const* d_in, const int* in_sizes, int n_in,
                              void* d_out, int out_size, void* d_ws, size_t ws_size,
                              hipStream_t stream)
{
    const float* p3b = (const float*)d_in[0];
    const float* p3c = (const float*)d_in[1];
    const float* p3k = (const float*)d_in[2];
    const float* p4b = (const float*)d_in[3];
    const float* p4c = (const float*)d_in[4];
    const float* p4k = (const float*)d_in[5];
    const float* p5b = (const float*)d_in[6];
    const float* p5c = (const float*)d_in[7];
    const float* p5k = (const float*)d_in[8];
    float* out = (float*)d_out;

    // workspace carve-up (256B aligned slabs)
    char* ws = (char*)d_ws;
    size_t off = 0;
    auto alloc = [&](size_t bytes) { size_t o = off; off += (bytes + 255) & ~(size_t)255; return o; };
    const size_t BN = (size_t)NBATCH * NTOT;
    uint64_t* keys      = (uint64_t*)(ws + alloc(BN * 8));
    float4*   boxes_cat = (float4*)  (ws + alloc(BN * 16));
    float*    score     = (float*)   (ws + alloc(BN * 4));
    int*      clsidx    = (int*)     (ws + alloc(BN * 4));
    uint32_t* sv        = (uint32_t*)(ws + alloc(BN * 4));
    float4*   sboxes    = (float4*)  (ws + alloc(BN * 16));
    float*    sscore    = (float*)   (ws + alloc(BN * 4));
    int*      scls      = (int*)     (ws + alloc(BN * 4));
    uint32_t* ssv       = (uint32_t*)(ws + alloc(BN * 4));
    u64*      rem64     = (u64*)     (ws + alloc((size_t)NBATCH * NW64 * 8));
    u64*      validbits = (u64*)     (ws + alloc((size_t)NBATCH * NW64 * 8));
    int*      nvalid    = (int*)     (ws + alloc(NBATCH * 4));
    u64*      diag      = (u64*)     (ws + alloc((size_t)NBATCH * NW64 * 64 * 8));
    u64*      sdiag     = (u64*)     (ws + alloc((size_t)NBATCH * NW64 * 64 * 8));
    u64*      mask      = (u64*)     (ws + alloc((size_t)NBATCH * NTOT * NW64 * 8));
    bool fast = (off <= ws_size);

    hipMemsetAsync(nvalid, 0, NBATCH * 4, stream);
    hipMemsetAsync(validbits, 0, (size_t)NBATCH * NW64 * 8, stream);

    int nblk = (int)((BN + 255) / 256);
    prep_kernel<<<nblk, 256, 0, stream>>>(p3b, p3c, p3k, p4b, p4c, p4k, p5b, p5c, p5k,
                                          keys, boxes_cat, score, clsidx, sv);

    dim3 rgrid((NTOT + 255) / 256, NBATCH);
    rank_kernel<<<rgrid, 256, 0, stream>>>(keys, boxes_cat, score, clsidx, sv,
                                           sboxes, sscore, scls, ssv, validbits, nvalid);

    if (fast) {
        dim3 mgrid((NW64 + 3) / 4, NW64, NBATCH);
        mask_build<<<mgrid, 256, 0, stream>>>(sboxes, mask, diag, sdiag);
        resolve_kernel<<<NBATCH, 1024, 0, stream>>>(mask, diag, sdiag, validbits, rem64);
    } else {
        hipMemsetAsync(rem64, 0, (size_t)NBATCH * NW64 * 8, stream);
        size_t smem = (size_t)LDS_CAP * 16 + (size_t)NW32 * 4 * 2;
        smem = (smem + 15) & ~(size_t)15;
        hipFuncSetAttribute((const void*)nms_kernel, hipFuncAttributeMaxDynamicSharedMemorySize, (int)smem);
        nms_kernel<<<NBATCH, 1024, smem, stream>>>(sboxes, ssv, nvalid, (uint32_t*)rem64);
    }

    out_kernel<<<nblk, 256, 0, stream>>>(sboxes, sscore, scls, ssv, rem64, out);
}

// Round 3
// 1075.896 us; speedup vs baseline: 1.1332x; 1.1332x over previous
//
#include <hip/hip_runtime.h>
#include <stdint.h>

#define NB3 8112
#define NB4 2028
#define NB5 507
#define NTOT 10647           // 8112 + 2028 + 507
#define NBATCH 4
#define NCLS 20
#define NW32 333             // ceil(10647 / 32)
#define NW64 167             // ceil(10647 / 64)
#define LDS_CAP 9984         // boxes staged in LDS (fallback kernel)
#define CONF_THR_F 0.1f
#define IOU_THR_F 0.45f

typedef unsigned long long u64;

// ---------------------------------------------------------------------------
// Kernel A: per-box score / class argmax / sort key
// ---------------------------------------------------------------------------
__global__ void prep_kernel(const float* __restrict__ p3b, const float* __restrict__ p3c, const float* __restrict__ p3k,
                            const float* __restrict__ p4b, const float* __restrict__ p4c, const float* __restrict__ p4k,
                            const float* __restrict__ p5b, const float* __restrict__ p5c, const float* __restrict__ p5k,
                            uint64_t* __restrict__ keys, float4* __restrict__ boxes_cat,
                            float* __restrict__ score, int* __restrict__ clsidx, uint32_t* __restrict__ svout)
{
#pragma clang fp contract(off)
    int idx = blockIdx.x * 256 + threadIdx.x;
    if (idx >= NBATCH * NTOT) return;
    int b = idx / NTOT;
    int i = idx - b * NTOT;

    const float* bx; const float* cf; const float* cl; int n, off;
    if (i < NB3)            { bx = p3b; cf = p3c; cl = p3k; n = NB3; off = i; }
    else if (i < NB3 + NB4) { bx = p4b; cf = p4c; cl = p4k; n = NB4; off = i - NB3; }
    else                    { bx = p5b; cf = p5c; cl = p5k; n = NB5; off = i - NB3 - NB4; }

    size_t e = (size_t)b * n + off;
    float4 box = *(const float4*)(bx + e * 4);
    float conf = cf[e];
    const float* c = cl + e * NCLS;
    float m = c[0]; int mi = 0;
    #pragma unroll
    for (int k = 1; k < NCLS; ++k) { float v = c[k]; if (v > m) { m = v; mi = k; } }

    bool valid = conf > CONF_THR_F;
    float s = valid ? conf * m : 0.0f;           // exact: single f32 mul, no fma
    uint32_t sb = __float_as_uint(s);            // s >= 0 -> bits monotonic
    keys[idx]      = ((uint64_t)sb << 32) | (uint32_t)(0xFFFFFFFFu - (uint32_t)i);
    boxes_cat[idx] = box;
    score[idx]     = s;
    clsidx[idx]    = mi;
    svout[idx]     = valid ? 1u : 0u;
}

// ---------------------------------------------------------------------------
// Kernel B: stable descending rank sort (rank = #keys strictly greater),
// scatter sorted arrays, build valid bitmap (u64 words) per image
// ---------------------------------------------------------------------------
__global__ void rank_kernel(const uint64_t* __restrict__ keys,
                            const float4* __restrict__ boxes_cat,
                            const float* __restrict__ score,
                            const int* __restrict__ clsidx,
                            const uint32_t* __restrict__ sv,
                            float4* __restrict__ sboxes, float* __restrict__ sscore,
                            int* __restrict__ scls, uint32_t* __restrict__ ssv,
                            u64* __restrict__ validbits, int* __restrict__ nvalid)
{
    int b = blockIdx.y;
    int i = blockIdx.x * 256 + threadIdx.x;
    const uint64_t* kb = keys + (size_t)b * NTOT;
    uint64_t mykey = (i < NTOT) ? kb[i] : 0ull;

    __shared__ uint64_t tile[256];
    int rank = 0;
    for (int t0 = 0; t0 < NTOT; t0 += 256) {
        int j = t0 + threadIdx.x;
        tile[threadIdx.x] = (j < NTOT) ? kb[j] : 0ull;   // 0 never > any real key
        __syncthreads();
        #pragma unroll 8
        for (int t = 0; t < 256; ++t) rank += (tile[t] > mykey) ? 1 : 0;
        __syncthreads();
    }

    if (i < NTOT) {
        size_t src = (size_t)b * NTOT + i;
        size_t dst = (size_t)b * NTOT + rank;
        sboxes[dst] = boxes_cat[src];
        sscore[dst] = score[src];
        scls[dst]   = clsidx[src];
        uint32_t v  = sv[src];
        ssv[dst]    = v;
        if (v) {
            atomicOr(&validbits[(size_t)b * NW64 + (rank >> 6)], 1ull << (rank & 63));
            atomicMax(&nvalid[b], rank + 1);
        }
    }
}

// ---------------------------------------------------------------------------
// Kernel C1 (fast path): build suppression bit-matrix + compact diag blocks
// + super-diagonal blocks.
// mask[(b*NTOT + i)*NW64 + c] = 64-bit word: bit k set iff IoU(i, c*64+k)>thr
// and (c*64+k) > i. Only upper-triangle chunks (c >= r) are written.
// diag [(b*NW64 + g)*64 + lane] = mask word of row g*64+lane at column-chunk g
// sdiag[(b*NW64 + g)*64 + lane] = mask word of row g*64+lane at column-chunk g+1
// (both coalesced copies for resolve_kernel's decision pipeline).
// ---------------------------------------------------------------------------
__global__ void __launch_bounds__(256) mask_build(const float4* __restrict__ sboxes,
                                                  u64* __restrict__ mask,
                                                  u64* __restrict__ diag,
                                                  u64* __restrict__ sdiag)
{
#pragma clang fp contract(off)
    int c = blockIdx.y;
    if (c < blockIdx.x * 4) return;              // whole block below diagonal
    int b = blockIdx.z;
    int sub = threadIdx.x >> 6;
    int lane = threadIdx.x & 63;
    int r = blockIdx.x * 4 + sub;

    __shared__ float4 cb[64];
    __shared__ float  ca[64];
    if (threadIdx.x < 64) {
        int j = c * 64 + threadIdx.x;
        float4 bj = sboxes[(size_t)b * NTOT + (j < NTOT ? j : NTOT - 1)];
        cb[threadIdx.x] = bj;
        ca[threadIdx.x] = (bj.z - bj.x) * (bj.w - bj.y);
    }
    __syncthreads();

    if (r >= NW64 || c < r) return;              // wave below diagonal / OOB
    int i = r * 64 + lane;
    float4 bi = sboxes[(size_t)b * NTOT + (i < NTOT ? i : NTOT - 1)];
    float ax1 = bi.x, ay1 = bi.y, ax2 = bi.z, ay2 = bi.w;
    float area_i = (ax2 - ax1) * (ay2 - ay1);

    u64 m = 0;
    #pragma unroll 8
    for (int k = 0; k < 64; ++k) {
        float4 bj = cb[k];
        float xx1 = fmaxf(bj.x, ax1);
        float yy1 = fmaxf(bj.y, ay1);
        float xx2 = fminf(bj.z, ax2);
        float yy2 = fminf(bj.w, ay2);
        float w = fmaxf(xx2 - xx1, 0.0f);
        float h = fmaxf(yy2 - yy1, 0.0f);
        float inter = w * h;
        float iou = inter / ((area_i + ca[k]) - inter);   // matches ref op order
        bool set = (iou > IOU_THR_F) && (c > r || k > lane) && (c * 64 + k < NTOT);
        m |= (u64)set << k;
    }
    if (i < NTOT) {
        mask[((size_t)b * NTOT + i) * NW64 + c] = m;
        if (c == r)     diag [((size_t)b * NW64 + r) * 64 + lane] = m;
        if (c == r + 1) sdiag[((size_t)b * NW64 + r) * 64 + lane] = m;
    }
}

// ---------------------------------------------------------------------------
// Kernel C2 (fast path): greedy resolve, one 1024-thread block per image.
// R2's pipeline (1 barrier/group, super-diagonal near-word, deferred far-word
// commit) but with the serial chain moved OFF the LDS pipe: pend/kept/w1 are
// wave-uniform scalars, and row words are pulled from the lane-distributed
// diag/superdiag registers with v_readlane (VALU latency) instead of
// ds_bpermute (+lgkmcnt round-trip). Chain step ~= s_ff1 + 4 readlane +
// scalar ops.
//   * decide(g) -> word g+1 via superdiag readlanes inside the chain.
//   * words g+2.. loaded at iteration g (predicated), carried ACROSS the
//     barrier, committed via sparse LDS atomicOr at iteration g+1.
//   * raw s_barrier (lgkmcnt drain only) keeps VMEM prefetches in flight.
//   * every wave runs the (uniform) chain redundantly and captures its own
//     kept-row slots (s == wv + 16t) -> no klist handoff.
//   * benign race on rem_s[g]: greedy(alive \ supp) == kept when supp is the
//     set suppressed by kept rows, so late-reading waves agree.
// ---------------------------------------------------------------------------
static __device__ __forceinline__ void bar_sync()
{
    asm volatile("s_waitcnt lgkmcnt(0)" ::: "memory");
    __builtin_amdgcn_s_barrier();
    asm volatile("" ::: "memory");
}

static __device__ __forceinline__ u64 rfl64(u64 x)
{
    uint32_t lo = __builtin_amdgcn_readfirstlane((uint32_t)x);
    uint32_t hi = __builtin_amdgcn_readfirstlane((uint32_t)(x >> 32));
    return ((u64)hi << 32) | (u64)lo;
}

static __device__ __forceinline__ u64 rl64(u64 x, int lane)
{
    uint32_t lo = (uint32_t)__builtin_amdgcn_readlane((int)(uint32_t)x, lane);
    uint32_t hi = (uint32_t)__builtin_amdgcn_readlane((int)(uint32_t)(x >> 32), lane);
    return ((u64)hi << 32) | (u64)lo;
}

__global__ void __launch_bounds__(1024) resolve_kernel(const u64* __restrict__ mask,
                                                       const u64* __restrict__ diag,
                                                       const u64* __restrict__ sdiag,
                                                       const u64* __restrict__ validbits,
                                                       u64* __restrict__ rem_out)
{
    int b = blockIdx.x;
    int tid = threadIdx.x;
    int lane = tid & 63;
    int wv = tid >> 6;
    const u64* M  = mask  + (size_t)b * NTOT * NW64;
    const u64* D  = diag  + (size_t)b * NW64 * 64;
    const u64* SD = sdiag + (size_t)b * NW64 * 64;
    const u64* V  = validbits + (size_t)b * NW64;

    __shared__ u64 rem_s[NW64 + 1];              // +1 pad absorbs g=last near-OR
    __shared__ u64 v_s[NW64];

    for (int t = tid; t < NW64; t += 1024) { rem_s[t] = 0ull; v_s[t] = V[t]; }
    if (tid == 0) rem_s[NW64] = 0ull;

    u64 dl  = D[lane];                           // diag word, group 0
    u64 sdl = SD[lane];                          // superdiag word, group 0

    u64 df[4][3];                                // deferred far-OR payload
    #pragma unroll
    for (int t = 0; t < 4; ++t) {
        #pragma unroll
        for (int c = 0; c < 3; ++c) df[t][c] = 0ull;
    }
    int r0 = 0, r1 = 0, r2 = 0, r3 = 0;          // captured kept-row slots

    bar_sync();

    for (int g = 0; g < NW64; ++g) {
        // 1. prefetch next group's diag/superdiag (stays in flight across bar)
        int gn = (g + 1 < NW64) ? g + 1 : g;
        u64 dn  = D [(size_t)gn * 64 + lane];
        u64 sdn = SD[(size_t)gn * 64 + lane];

        // 2. decide: scalar greedy chain (uniform), identical in every wave.
        //    Row words come from readlane on the lane-distributed dl/sdl --
        //    no LDS round-trips on the dependency chain.
        u64 alive = rfl64(v_s[g] & ~rem_s[g]);
        u64 kept = 0, pend = alive, w1 = 0;
        int s = 0;
        while (pend) {
            int i = __ffsll((unsigned long long)pend) - 1;
            kept |= 1ull << i;
            u64 d = rl64(dl, i);
            w1 |= rl64(sdl, i);
            r0 = (s == wv)      ? i : r0;
            r1 = (s == wv + 16) ? i : r1;
            r2 = (s == wv + 32) ? i : r2;
            r3 = (s == wv + 48) ? i : r3;
            pend &= ~(d | (1ull << i));
            ++s;
        }
        int nk = s;

        // 3. record in-group suppressions + near word g+1
        if (tid == 0) {
            u64 supp = alive & ~kept;
            if (supp) atomicOr((unsigned long long*)&rem_s[g],     (unsigned long long)supp);
            if (w1)   atomicOr((unsigned long long*)&rem_s[g + 1], (unsigned long long)w1);
        }

        // 4. commit deferred far-ORs from the previous group (targets >= g+1;
        //    sparse -- most df words are zero and skip the atomic)
        #pragma unroll
        for (int t = 0; t < 4; ++t) {
            #pragma unroll
            for (int c = 0; c < 3; ++c) {
                if (df[t][c])
                    atomicOr((unsigned long long*)&rem_s[g + 1 + (c << 6) + lane],
                             (unsigned long long)df[t][c]);
            }
        }

        // 5. issue this group's far loads (words g+2..166), predicated to 0;
        //    results are consumed one iteration later (step 4 of g+1)
        #pragma unroll
        for (int t = 0; t < 4; ++t) {
            bool has = (wv + (t << 4)) < nk;
            int  rr  = (t == 0) ? r0 : (t == 1) ? r1 : (t == 2) ? r2 : r3;
            const u64* R = M + (size_t)(g * 64 + rr) * NW64;
            #pragma unroll
            for (int c = 0; c < 3; ++c) {
                int w = g + 2 + (c << 6) + lane;
                df[t][c] = (has && w < NW64) ? R[w] : 0ull;
            }
        }

        bar_sync();                               // LDS coherent; VMEM in flight
        dl = dn; sdl = sdn;
    }
    // df from the final groups target words >= NW64 -> predicated to zero. OK.

    for (int t = tid; t < NW64; t += 1024)
        rem_out[(size_t)b * NW64 + t] = rem_s[t];
}

// ---------------------------------------------------------------------------
// Fallback (small ws): original single-block NMS. Writes u32 words into the
// same u64 rem buffer (little-endian layout makes bit positions identical).
// ---------------------------------------------------------------------------
extern __shared__ unsigned char nms_smem[];

__global__ void __launch_bounds__(1024) nms_kernel(const float4* __restrict__ sboxes,
                                                   const uint32_t* __restrict__ ssv,
                                                   const int* __restrict__ nvalid_arr,
                                                   uint32_t* __restrict__ supp_out)
{
#pragma clang fp contract(off)
    int b = blockIdx.x;
    float4*   lbox = (float4*)nms_smem;
    uint32_t* supp = (uint32_t*)(nms_smem + (size_t)LDS_CAP * 16);
    uint32_t* svb  = supp + NW32;

    int nv = nvalid_arr[b];
    const float4* gb = sboxes + (size_t)b * NTOT;
    const uint32_t* gv = ssv + (size_t)b * NTOT;

    for (int t = threadIdx.x; t < NW32; t += 1024) { supp[t] = 0u; svb[t] = 0u; }
    __syncthreads();
    for (int t = threadIdx.x; t < nv; t += 1024) {
        if (t < LDS_CAP) lbox[t] = gb[t];
        if (gv[t]) atomicOr(&svb[t >> 5], 1u << (t & 31));
    }
    __syncthreads();

    for (int i = 0; i < nv; ++i) {
        uint32_t sw = supp[i >> 5];
        if ((sw >> (i & 31)) & 1u) continue;
        uint32_t vw = svb[i >> 5];
        if (!((vw >> (i & 31)) & 1u)) continue;

        float4 bi = (i < LDS_CAP) ? lbox[i] : gb[i];
        float ax1 = bi.x, ay1 = bi.y, ax2 = bi.z, ay2 = bi.w;
        float area_i = (ax2 - ax1) * (ay2 - ay1);

        for (int j = i + 1 + (int)threadIdx.x; j < nv; j += 1024) {
            float4 bj = (j < LDS_CAP) ? lbox[j] : gb[j];
            float xx1 = fmaxf(bj.x, ax1);
            float yy1 = fmaxf(bj.y, ay1);
            float xx2 = fminf(bj.z, ax2);
            float yy2 = fminf(bj.w, ay2);
            float w = fmaxf(xx2 - xx1, 0.0f);
            float h = fmaxf(yy2 - yy1, 0.0f);
            float inter  = w * h;
            float area_j = (bj.z - bj.x) * (bj.w - bj.y);
            float iou = inter / ((area_i + area_j) - inter);
            if (iou > IOU_THR_F) atomicOr(&supp[j >> 5], 1u << (j & 31));
        }
        __syncthreads();
    }

    __syncthreads();
    // u64 layout: u32 word w of image b lives at u32-index b*(2*NW64) + w
    for (int t = threadIdx.x; t < NW32; t += 1024)
        supp_out[(size_t)b * (2 * NW64) + t] = supp[t];
}

// ---------------------------------------------------------------------------
// Kernel D: assemble outputs: dets [B,N,6] then keep [B,N] (as 0/1 floats)
// ---------------------------------------------------------------------------
__global__ void out_kernel(const float4* __restrict__ sboxes, const float* __restrict__ sscore,
                           const int* __restrict__ scls, const uint32_t* __restrict__ ssv,
                           const u64* __restrict__ rem, float* __restrict__ out)
{
    int idx = blockIdx.x * 256 + threadIdx.x;
    if (idx >= NBATCH * NTOT) return;
    int b = idx / NTOT;
    int p = idx - b * NTOT;

    float4 box = sboxes[idx];
    u64 rw = rem[(size_t)b * NW64 + (p >> 6)];
    bool keep = (ssv[idx] != 0u) && !((rw >> (p & 63)) & 1ull);
    float sc = keep ? sscore[idx] : 0.0f;

    float* d = out + (size_t)idx * 6;
    d[0] = box.x; d[1] = box.y; d[2] = box.z; d[3] = box.w;
    d[4] = sc;    d[5] = (float)scls[idx];
    out[(size_t)NBATCH * NTOT * 6 + idx] = keep ? 1.0f : 0.0f;
}

// ---------------------------------------------------------------------------
extern "C" void kernel_launch(void* const* d_in, const int* in_sizes, int n_in,
                              void* d_out, int out_size, void* d_ws, size_t ws_size,
                              hipStream_t stream)
{
    const float* p3b = (const float*)d_in[0];
    const float* p3c = (const float*)d_in[1];
    const float* p3k = (const float*)d_in[2];
    const float* p4b = (const float*)d_in[3];
    const float* p4c = (const float*)d_in[4];
    const float* p4k = (const float*)d_in[5];
    const float* p5b = (const float*)d_in[6];
    const float* p5c = (const float*)d_in[7];
    const float* p5k = (const float*)d_in[8];
    float* out = (float*)d_out;

    // workspace carve-up (256B aligned slabs)
    char* ws = (char*)d_ws;
    size_t off = 0;
    auto alloc = [&](size_t bytes) { size_t o = off; off += (bytes + 255) & ~(size_t)255; return o; };
    const size_t BN = (size_t)NBATCH * NTOT;
    uint64_t* keys      = (uint64_t*)(ws + alloc(BN * 8));
    float4*   boxes_cat = (float4*)  (ws + alloc(BN * 16));
    float*    score     = (float*)   (ws + alloc(BN * 4));
    int*      clsidx    = (int*)     (ws + alloc(BN * 4));
    uint32_t* sv        = (uint32_t*)(ws + alloc(BN * 4));
    float4*   sboxes    = (float4*)  (ws + alloc(BN * 16));
    float*    sscore    = (float*)   (ws + alloc(BN * 4));
    int*      scls      = (int*)     (ws + alloc(BN * 4));
    uint32_t* ssv       = (uint32_t*)(ws + alloc(BN * 4));
    u64*      rem64     = (u64*)     (ws + alloc((size_t)NBATCH * NW64 * 8));
    u64*      validbits = (u64*)     (ws + alloc((size_t)NBATCH * NW64 * 8));
    int*      nvalid    = (int*)     (ws + alloc(NBATCH * 4));
    u64*      diag      = (u64*)     (ws + alloc((size_t)NBATCH * NW64 * 64 * 8));
    u64*      sdiag     = (u64*)     (ws + alloc((size_t)NBATCH * NW64 * 64 * 8));
    u64*      mask      = (u64*)     (ws + alloc((size_t)NBATCH * NTOT * NW64 * 8));
    bool fast = (off <= ws_size);

    hipMemsetAsync(nvalid, 0, NBATCH * 4, stream);
    hipMemsetAsync(validbits, 0, (size_t)NBATCH * NW64 * 8, stream);

    int nblk = (int)((BN + 255) / 256);
    prep_kernel<<<nblk, 256, 0, stream>>>(p3b, p3c, p3k, p4b, p4c, p4k, p5b, p5c, p5k,
                                          keys, boxes_cat, score, clsidx, sv);

    dim3 rgrid((NTOT + 255) / 256, NBATCH);
    rank_kernel<<<rgrid, 256, 0, stream>>>(keys, boxes_cat, score, clsidx, sv,
                                           sboxes, sscore, scls, ssv, validbits, nvalid);

    if (fast) {
        dim3 mgrid((NW64 + 3) / 4, NW64, NBATCH);
        mask_build<<<mgrid, 256, 0, stream>>>(sboxes, mask, diag, sdiag);
        resolve_kernel<<<NBATCH, 1024, 0, stream>>>(mask, diag, sdiag, validbits, rem64);
    } else {
        hipMemsetAsync(rem64, 0, (size_t)NBATCH * NW64 * 8, stream);
        size_t smem = (size_t)LDS_CAP * 16 + (size_t)NW32 * 4 * 2;
        smem = (smem + 15) & ~(size_t)15;
        hipFuncSetAttribute((const void*)nms_kernel, hipFuncAttributeMaxDynamicSharedMemorySize, (int)smem);
        nms_kernel<<<NBATCH, 1024, smem, stream>>>(sboxes, ssv, nvalid, (uint32_t*)rem64);
    }

    out_kernel<<<nblk, 256, 0, stream>>>(sboxes, sscore, scls, ssv, rem64, out);
}